// Round 11
// baseline (219.105 us; speedup 1.0000x reference)
//
#include <hip/hip_runtime.h>
#include <cstdint>

// GF(2) encoder: out[b][n] = parity( x_row[b] & g_row[n] ).
// B=131072, K=512, N=1024.
//
// R11 = R10 with the nontemporal-store type fixed (clang ext_vector, not
// HIP_vector_type).
// Structure: ONE fused kernel, 2-col geometry for TLP.
//  - R9 (4-col, LB(256,4), ~100 live VGPR) = 4 waves/SIMD -> HBM latency
//    exposed (203 us vs ~120 floor).
//  - R10/R11: 512 thr x 2 cols, g=32 VGPR, live ~60 <= cap 64 (LB(512,8),
//    R8-proven budget) -> 8 waves/SIMD. Ballot packs x directly into
//    SGPRs (no LDS/barrier/SMEM). Nontemporal stores keep the 512 MB
//    write stream from thrashing L2 (8 waves/block re-read x via L2).
// Component-major bit order identical to pack256 (G): chunk of 256 floats
// -> 4 u64, word j bit i = elem[i*4+j]; row = 2 chunks = 8 u64.

typedef float f32x2 __attribute__((ext_vector_type(2)));

// ---------------------------------------------------------------------------
// Pack G only: one wave per 256-float chunk. nChunks = N*K/256 = 2048.
__global__ void pack256_kernel(const float* __restrict__ in,
                               unsigned long long* __restrict__ out,
                               int nChunks) {
    const int chunk = blockIdx.x * (blockDim.x >> 6) + (threadIdx.x >> 6);
    const int lane = threadIdx.x & 63;
    if (chunk >= nChunks) return;
    const float4 v =
        reinterpret_cast<const float4*>(in + (size_t)chunk * 256)[lane];
    unsigned long long m0 = __ballot(v.x != 0.0f);
    unsigned long long m1 = __ballot(v.y != 0.0f);
    unsigned long long m2 = __ballot(v.z != 0.0f);
    unsigned long long m3 = __ballot(v.w != 0.0f);
    if (lane == 0) {
        unsigned long long* o = out + (size_t)chunk * 4;
        o[0] = m0; o[1] = m1; o[2] = m2; o[3] = m3;
    }
}

// ---------------------------------------------------------------------------
// Fused encode: 512 threads, 2 cols/thread (block covers N=1024).
// Each wave streams the block's 64 x-rows (2 float4/lane/row, prefetched
// one row ahead), ballots them into 8 wave-uniform u64 (SGPR pairs), and
// AND/XOR-folds against G held as u64[2][8] in VGPRs. Nontemporal f32x2
// stores. Live VGPR ~60: g 32 + prefetch 8 + cur 8 + accs/addr ~12.
__global__ __launch_bounds__(512, 8) void gf2_fused_kernel(
    const float* __restrict__ x,      // [B][512] 0/1 floats
    const unsigned long long* __restrict__ gp,  // [N][8] packed G rows
    float* __restrict__ out) {        // [B][1024]
    const int tid = threadIdx.x;
    const int lane = tid & 63;
    const long long b0 = (long long)blockIdx.x * 64;

    // This thread's 2 G rows (32 VGPRs). G packed = 64 KiB -> L2-resident.
    unsigned long long g[2][8];
#pragma unroll
    for (int j = 0; j < 2; ++j) {
        const unsigned long long* gr = gp + (size_t)(tid * 2 + j) * 8;
#pragma unroll
        for (int i = 0; i < 8; ++i) g[j][i] = gr[i];
    }

    // Wave-private x stream, software-prefetched one row ahead.
    const float* xr = x + b0 * 512 + lane * 4;
    float4 p0 = *reinterpret_cast<const float4*>(xr);
    float4 p1 = *reinterpret_cast<const float4*>(xr + 256);

    float* orow = out + b0 * 1024;
    for (int r = 0; r < 64; ++r) {
        const float4 c0 = p0, c1 = p1;
        if (r < 63) {
            xr += 512;
            p0 = *reinterpret_cast<const float4*>(xr);
            p1 = *reinterpret_cast<const float4*>(xr + 256);
        }
        // Ballot-pack this row into 8 wave-uniform u64 (SGPR pairs).
        unsigned long long m[8];
        m[0] = __ballot(c0.x != 0.0f);
        m[1] = __ballot(c0.y != 0.0f);
        m[2] = __ballot(c0.z != 0.0f);
        m[3] = __ballot(c0.w != 0.0f);
        m[4] = __ballot(c1.x != 0.0f);
        m[5] = __ballot(c1.y != 0.0f);
        m[6] = __ballot(c1.z != 0.0f);
        m[7] = __ballot(c1.w != 0.0f);

        unsigned long long a0 = 0, a1 = 0;
#pragma unroll
        for (int i = 0; i < 8; ++i) {
            a0 ^= m[i] & g[0][i];
            a1 ^= m[i] & g[1][i];
        }
        const uint32_t f0 = (uint32_t)a0 ^ (uint32_t)(a0 >> 32);
        const uint32_t f1 = (uint32_t)a1 ^ (uint32_t)(a1 >> 32);
        f32x2 o;
        o.x = (float)(__popc(f0) & 1);
        o.y = (float)(__popc(f1) & 1);
        __builtin_nontemporal_store(o, reinterpret_cast<f32x2*>(orow) + tid);
        orow += 1024;
    }
}

// ---------------------------------------------------------------------------
extern "C" void kernel_launch(void* const* d_in, const int* in_sizes, int n_in,
                              void* d_out, int out_size, void* d_ws, size_t ws_size,
                              hipStream_t stream) {
    const float* x = (const float*)d_in[0];   // [B][512]
    const float* G = (const float*)d_in[1];   // [N][512]
    float* out = (float*)d_out;

    const int B = 131072;
    // Workspace: gp (64 KiB)
    unsigned long long* gp64 = (unsigned long long*)d_ws;

    // Pack G: 2048 chunks, 4 waves/block -> 512 blocks.
    pack256_kernel<<<512, 256, 0, stream>>>(G, gp64, 2048);
    // Fused ballot-pack + encode: one block per 64 rows.
    gf2_fused_kernel<<<B / 64, 512, 0, stream>>>(x, gp64, out);
}

// Round 12
// 211.139 us; speedup vs baseline: 1.0377x; 1.0377x over previous
//
#include <hip/hip_runtime.h>
#include <cstdint>

// GF(2) encoder: out[b][n] = parity( x_row[b] & g_row[n] ).
// B=131072, K=512, N=1024.
//
// R12 = R9 (best, 203us: fused ballot, 4-col, 256thr, LB(256,4)) +
// depth-2 software prefetch with NAMED buffers (no runtime-indexed float4
// arrays -> no scratch, rule #20). Each row's global loads are issued ~2
// compute-rows (~580cy) before use -> HBM latency covered per-wave, not
// just via TLP. Plain float4 stores (R11's nt/float2 regressed).
// Component-major bit order identical to pack256 (G): chunk of 256 floats
// -> 4 u64, word j bit i = elem[i*4+j]; row = 2 chunks = 8 u64 = 16 u32.

// ---------------------------------------------------------------------------
// Pack G only: one wave per 256-float chunk. nChunks = N*K/256 = 2048.
__global__ void pack256_kernel(const float* __restrict__ in,
                               unsigned long long* __restrict__ out,
                               int nChunks) {
    const int chunk = blockIdx.x * (blockDim.x >> 6) + (threadIdx.x >> 6);
    const int lane = threadIdx.x & 63;
    if (chunk >= nChunks) return;
    const float4 v =
        reinterpret_cast<const float4*>(in + (size_t)chunk * 256)[lane];
    unsigned long long m0 = __ballot(v.x != 0.0f);
    unsigned long long m1 = __ballot(v.y != 0.0f);
    unsigned long long m2 = __ballot(v.z != 0.0f);
    unsigned long long m3 = __ballot(v.w != 0.0f);
    if (lane == 0) {
        unsigned long long* o = out + (size_t)chunk * 4;
        o[0] = m0; o[1] = m1; o[2] = m2; o[3] = m3;
    }
}

// ---------------------------------------------------------------------------
// Fused encode: 256 threads, 4 cols/thread (block covers N=1024).
// Each wave streams the block's 64 x-rows (2 float4/lane/row), ballots them
// into 8 wave-uniform u64 (SGPRs), AND/XOR-folds against G (u64[4][8], 64
// VGPRs). Depth-2 prefetch: rows r+2/r+3 in flight while computing r/r+1.
__global__ __launch_bounds__(256, 4) void gf2_fused_kernel(
    const float* __restrict__ x,                // [B][512] 0/1 floats
    const unsigned long long* __restrict__ gp,  // [N][8] packed G rows
    float* __restrict__ out) {                  // [B][1024]
    const int tid = threadIdx.x;
    const int lane = tid & 63;
    const long long b0 = (long long)blockIdx.x * 64;

    // This thread's 4 G rows (64 VGPRs). G packed = 64 KiB -> L2-resident.
    unsigned long long g[4][8];
#pragma unroll
    for (int j = 0; j < 4; ++j) {
        const unsigned long long* gr = gp + (size_t)(tid * 4 + j) * 8;
#pragma unroll
        for (int i = 0; i < 8; ++i) g[j][i] = gr[i];
    }

    const float* xr = x + b0 * 512 + lane * 4;   // this lane's slice of row 0
    float* orow = out + b0 * 1024;

#define LOADROW(v0, v1, R)                                              \
    do {                                                                \
        v0 = *reinterpret_cast<const float4*>(xr + (size_t)(R)*512);    \
        v1 = *reinterpret_cast<const float4*>(xr + (size_t)(R)*512 + 256); \
    } while (0)

#define PROCESS(c0, c1)                                                 \
    do {                                                                \
        unsigned long long m[8];                                        \
        m[0] = __ballot(c0.x != 0.0f);                                  \
        m[1] = __ballot(c0.y != 0.0f);                                  \
        m[2] = __ballot(c0.z != 0.0f);                                  \
        m[3] = __ballot(c0.w != 0.0f);                                  \
        m[4] = __ballot(c1.x != 0.0f);                                  \
        m[5] = __ballot(c1.y != 0.0f);                                  \
        m[6] = __ballot(c1.z != 0.0f);                                  \
        m[7] = __ballot(c1.w != 0.0f);                                  \
        unsigned long long a0 = 0, a1 = 0, a2 = 0, a3 = 0;              \
        _Pragma("unroll") for (int i = 0; i < 8; ++i) {                 \
            a0 ^= m[i] & g[0][i];                                       \
            a1 ^= m[i] & g[1][i];                                       \
            a2 ^= m[i] & g[2][i];                                       \
            a3 ^= m[i] & g[3][i];                                       \
        }                                                               \
        float4 o;                                                       \
        o.x = (float)((__popcll(a0)) & 1);                              \
        o.y = (float)((__popcll(a1)) & 1);                              \
        o.z = (float)((__popcll(a2)) & 1);                              \
        o.w = (float)((__popcll(a3)) & 1);                              \
        reinterpret_cast<float4*>(orow)[tid] = o;                       \
        orow += 1024;                                                   \
    } while (0)

    float4 a0, a1, b0f, b1f;
    LOADROW(a0, a1, 0);
    LOADROW(b0f, b1f, 1);

    for (int i = 0; i < 32; ++i) {
        const float4 c0 = a0, c1 = a1;
        if (i < 31) LOADROW(a0, a1, 2 * i + 2);
        PROCESS(c0, c1);
        const float4 d0 = b0f, d1 = b1f;
        if (i < 31) LOADROW(b0f, b1f, 2 * i + 3);
        PROCESS(d0, d1);
    }
#undef LOADROW
#undef PROCESS
}

// ---------------------------------------------------------------------------
extern "C" void kernel_launch(void* const* d_in, const int* in_sizes, int n_in,
                              void* d_out, int out_size, void* d_ws, size_t ws_size,
                              hipStream_t stream) {
    const float* x = (const float*)d_in[0];   // [B][512]
    const float* G = (const float*)d_in[1];   // [N][512]
    float* out = (float*)d_out;

    const int B = 131072;
    // Workspace: gp (64 KiB)
    unsigned long long* gp64 = (unsigned long long*)d_ws;

    // Pack G: 2048 chunks, 4 waves/block -> 512 blocks.
    pack256_kernel<<<512, 256, 0, stream>>>(G, gp64, 2048);
    // Fused ballot-pack + encode: one block per 64 rows.
    gf2_fused_kernel<<<B / 64, 256, 0, stream>>>(x, gp64, out);
}

// Round 13
// 187.351 us; speedup vs baseline: 1.1695x; 1.1270x over previous
//
#include <hip/hip_runtime.h>
#include <cstdint>

// GF(2) encoder: out[b][n] = parity( x_row[b] & g_row[n] ).
// B=131072, K=512, N=1024.
//
// R13 = R9 (champion, 203us: fused ballot-pack, 4-col, 256thr, LB(256,4),
// depth-1 prefetch) with ONE change: nontemporal float4 stores.
// Theory: the 512 MB write stream write-allocates in the 4 MB/XCD L2 and
// evicts x lines between the 4 waves' redundant re-reads -> real HBM
// traffic ~1.5 GB (~7.3 TB/s at 203us = already HBM-walled with 2x excess
// traffic). nt stores bypass L2 -> x stays resident -> ~0.77 GB traffic.
// Single-variable A/B vs R9 (R11's nt test was confounded by 2-col geom).
// Component-major bit order identical to pack256 (G): chunk of 256 floats
// -> 4 u64, word j bit i = elem[i*4+j]; row = 2 chunks = 8 u64 = 16 u32.

typedef float f32x4 __attribute__((ext_vector_type(4)));

// ---------------------------------------------------------------------------
// Pack G only: one wave per 256-float chunk. nChunks = N*K/256 = 2048.
__global__ void pack256_kernel(const float* __restrict__ in,
                               unsigned long long* __restrict__ out,
                               int nChunks) {
    const int chunk = blockIdx.x * (blockDim.x >> 6) + (threadIdx.x >> 6);
    const int lane = threadIdx.x & 63;
    if (chunk >= nChunks) return;
    const float4 v =
        reinterpret_cast<const float4*>(in + (size_t)chunk * 256)[lane];
    unsigned long long m0 = __ballot(v.x != 0.0f);
    unsigned long long m1 = __ballot(v.y != 0.0f);
    unsigned long long m2 = __ballot(v.z != 0.0f);
    unsigned long long m3 = __ballot(v.w != 0.0f);
    if (lane == 0) {
        unsigned long long* o = out + (size_t)chunk * 4;
        o[0] = m0; o[1] = m1; o[2] = m2; o[3] = m3;
    }
}

// ---------------------------------------------------------------------------
// Fused encode: 256 threads, 4 cols/thread (block covers N=1024).
// Each wave streams the block's 64 x-rows (2 float4/lane/row, prefetched
// one row ahead), ballots them into 16 wave-uniform u32 (SGPRs), and
// AND/XOR-folds against G fragments held in VGPRs. Nontemporal f32x4
// stores (bypass L2, preserve x residency).
__global__ __launch_bounds__(256, 4) void gf2_fused_kernel(
    const float* __restrict__ x,      // [B][512] 0/1 floats
    const uint32_t* __restrict__ gp,  // [N][16] packed G rows
    float* __restrict__ out) {        // [B][1024]
    const int tid = threadIdx.x;
    const int lane = tid & 63;
    const long long b0 = (long long)blockIdx.x * 64;

    // This thread's 4 G rows (64 VGPRs). G packed = 64 KiB -> L2-resident.
    uint32_t g[4][16];
#pragma unroll
    for (int j = 0; j < 4; ++j) {
        const uint4* gr =
            reinterpret_cast<const uint4*>(gp + (size_t)(tid * 4 + j) * 16);
        uint4 a = gr[0], b = gr[1], c = gr[2], d = gr[3];
        g[j][0] = a.x;  g[j][1] = a.y;  g[j][2] = a.z;  g[j][3] = a.w;
        g[j][4] = b.x;  g[j][5] = b.y;  g[j][6] = b.z;  g[j][7] = b.w;
        g[j][8] = c.x;  g[j][9] = c.y;  g[j][10] = c.z; g[j][11] = c.w;
        g[j][12] = d.x; g[j][13] = d.y; g[j][14] = d.z; g[j][15] = d.w;
    }

    // Wave-private x stream, software-prefetched one row ahead.
    const float* xr = x + b0 * 512 + lane * 4;
    float4 p0 = *reinterpret_cast<const float4*>(xr);
    float4 p1 = *reinterpret_cast<const float4*>(xr + 256);

    for (int r = 0; r < 64; ++r) {
        const float4 c0 = p0, c1 = p1;
        if (r < 63) {
            xr += 512;
            p0 = *reinterpret_cast<const float4*>(xr);
            p1 = *reinterpret_cast<const float4*>(xr + 256);
        }
        // Ballot-pack this row into 16 wave-uniform u32 (SGPRs).
        unsigned long long m0 = __ballot(c0.x != 0.0f);
        unsigned long long m1 = __ballot(c0.y != 0.0f);
        unsigned long long m2 = __ballot(c0.z != 0.0f);
        unsigned long long m3 = __ballot(c0.w != 0.0f);
        unsigned long long m4 = __ballot(c1.x != 0.0f);
        unsigned long long m5 = __ballot(c1.y != 0.0f);
        unsigned long long m6 = __ballot(c1.z != 0.0f);
        unsigned long long m7 = __ballot(c1.w != 0.0f);
        const uint32_t xv[16] = {
            (uint32_t)m0, (uint32_t)(m0 >> 32),
            (uint32_t)m1, (uint32_t)(m1 >> 32),
            (uint32_t)m2, (uint32_t)(m2 >> 32),
            (uint32_t)m3, (uint32_t)(m3 >> 32),
            (uint32_t)m4, (uint32_t)(m4 >> 32),
            (uint32_t)m5, (uint32_t)(m5 >> 32),
            (uint32_t)m6, (uint32_t)(m6 >> 32),
            (uint32_t)m7, (uint32_t)(m7 >> 32)};

        uint32_t a0 = 0, a1 = 0, a2 = 0, a3 = 0;
#pragma unroll
        for (int i = 0; i < 16; ++i) {
            a0 ^= xv[i] & g[0][i];
            a1 ^= xv[i] & g[1][i];
            a2 ^= xv[i] & g[2][i];
            a3 ^= xv[i] & g[3][i];
        }
        f32x4 o;
        o.x = (float)(__popc(a0) & 1);
        o.y = (float)(__popc(a1) & 1);
        o.z = (float)(__popc(a2) & 1);
        o.w = (float)(__popc(a3) & 1);
        __builtin_nontemporal_store(
            o, reinterpret_cast<f32x4*>(out + (size_t)(b0 + r) * 1024) + tid);
    }
}

// ---------------------------------------------------------------------------
extern "C" void kernel_launch(void* const* d_in, const int* in_sizes, int n_in,
                              void* d_out, int out_size, void* d_ws, size_t ws_size,
                              hipStream_t stream) {
    const float* x = (const float*)d_in[0];   // [B][512]
    const float* G = (const float*)d_in[1];   // [N][512]
    float* out = (float*)d_out;

    const int B = 131072;
    // Workspace: gp (64 KiB)
    unsigned long long* gp64 = (unsigned long long*)d_ws;

    // Pack G: 2048 chunks, 4 waves/block -> 512 blocks.
    pack256_kernel<<<512, 256, 0, stream>>>(G, gp64, 2048);
    // Fused ballot-pack + encode: one block per 64 rows.
    gf2_fused_kernel<<<B / 64, 256, 0, stream>>>(
        x, (const uint32_t*)gp64, out);
}

// Round 14
// 159.334 us; speedup vs baseline: 1.3751x; 1.1758x over previous
//
#include <hip/hip_runtime.h>
#include <cstdint>

// GF(2) encoder: out[b][n] = parity( x_row[b] & g_row[n] ).
// B=131072, K=512, N=1024.
//
// R14 = R13 (187us: fused ballot, 4-col, nt-stores) with read redundancy
// ELIMINATED: each wave packs 16 exclusive x rows -> LDS (1KB/wave, one
// barrier), compute phase reads packed rows via broadcast ds_read_b128.
// x is fetched from HBM exactly once (256 MB). Falsifies the "redundant
// re-reads miss L2" theory for the remaining ~50us over the stream floor.
// Component-major bit order identical to pack256 (G): chunk of 256 floats
// -> 4 u64, word j bit i = elem[i*4+j]; row = 2 chunks = 8 u64 = 16 u32.

typedef float f32x4 __attribute__((ext_vector_type(4)));

// ---------------------------------------------------------------------------
// Pack G only: one wave per 256-float chunk. nChunks = N*K/256 = 2048.
__global__ void pack256_kernel(const float* __restrict__ in,
                               unsigned long long* __restrict__ out,
                               int nChunks) {
    const int chunk = blockIdx.x * (blockDim.x >> 6) + (threadIdx.x >> 6);
    const int lane = threadIdx.x & 63;
    if (chunk >= nChunks) return;
    const float4 v =
        reinterpret_cast<const float4*>(in + (size_t)chunk * 256)[lane];
    unsigned long long m0 = __ballot(v.x != 0.0f);
    unsigned long long m1 = __ballot(v.y != 0.0f);
    unsigned long long m2 = __ballot(v.z != 0.0f);
    unsigned long long m3 = __ballot(v.w != 0.0f);
    if (lane == 0) {
        unsigned long long* o = out + (size_t)chunk * 4;
        o[0] = m0; o[1] = m1; o[2] = m2; o[3] = m3;
    }
}

// ---------------------------------------------------------------------------
// Fused encode: 256 threads, 4 cols/thread (block covers N=1024).
// Pack phase: wave wv ballot-packs rows [wv*16, wv*16+16) (exclusive),
// lane 0 writes 64B/row to LDS. One barrier. Compute phase: per row, 4
// broadcast ds_read_b128 deliver the packed row; AND/XOR vs G in VGPRs;
// nontemporal f32x4 stores.
__global__ __launch_bounds__(256, 4) void gf2_fused_kernel(
    const float* __restrict__ x,      // [B][512] 0/1 floats
    const uint32_t* __restrict__ gp,  // [N][16] packed G rows
    float* __restrict__ out) {        // [B][1024]
    __shared__ uint32_t xl[64 * 16];  // 64 rows x 16 u32 = 4 KiB

    const int tid = threadIdx.x;
    const int lane = tid & 63;
    const int wv = tid >> 6;
    const long long b0 = (long long)blockIdx.x * 64;

    // This thread's 4 G rows (64 VGPRs). G packed = 64 KiB -> L2-resident.
    uint32_t g[4][16];
#pragma unroll
    for (int j = 0; j < 4; ++j) {
        const uint4* gr =
            reinterpret_cast<const uint4*>(gp + (size_t)(tid * 4 + j) * 16);
        uint4 a = gr[0], b = gr[1], c = gr[2], d = gr[3];
        g[j][0] = a.x;  g[j][1] = a.y;  g[j][2] = a.z;  g[j][3] = a.w;
        g[j][4] = b.x;  g[j][5] = b.y;  g[j][6] = b.z;  g[j][7] = b.w;
        g[j][8] = c.x;  g[j][9] = c.y;  g[j][10] = c.z; g[j][11] = c.w;
        g[j][12] = d.x; g[j][13] = d.y; g[j][14] = d.z; g[j][15] = d.w;
    }

    // ---- Pack phase: 16 exclusive rows per wave, depth-1 prefetch. ----
    {
        const float* xr = x + (b0 + wv * 16) * 512 + lane * 4;
        float4 p0 = *reinterpret_cast<const float4*>(xr);
        float4 p1 = *reinterpret_cast<const float4*>(xr + 256);
        for (int r = 0; r < 16; ++r) {
            const float4 c0 = p0, c1 = p1;
            if (r < 15) {
                xr += 512;
                p0 = *reinterpret_cast<const float4*>(xr);
                p1 = *reinterpret_cast<const float4*>(xr + 256);
            }
            unsigned long long m0 = __ballot(c0.x != 0.0f);
            unsigned long long m1 = __ballot(c0.y != 0.0f);
            unsigned long long m2 = __ballot(c0.z != 0.0f);
            unsigned long long m3 = __ballot(c0.w != 0.0f);
            unsigned long long m4 = __ballot(c1.x != 0.0f);
            unsigned long long m5 = __ballot(c1.y != 0.0f);
            unsigned long long m6 = __ballot(c1.z != 0.0f);
            unsigned long long m7 = __ballot(c1.w != 0.0f);
            if (lane == 0) {
                uint4* dst = reinterpret_cast<uint4*>(&xl[(wv * 16 + r) * 16]);
                dst[0] = make_uint4((uint32_t)m0, (uint32_t)(m0 >> 32),
                                    (uint32_t)m1, (uint32_t)(m1 >> 32));
                dst[1] = make_uint4((uint32_t)m2, (uint32_t)(m2 >> 32),
                                    (uint32_t)m3, (uint32_t)(m3 >> 32));
                dst[2] = make_uint4((uint32_t)m4, (uint32_t)(m4 >> 32),
                                    (uint32_t)m5, (uint32_t)(m5 >> 32));
                dst[3] = make_uint4((uint32_t)m6, (uint32_t)(m6 >> 32),
                                    (uint32_t)m7, (uint32_t)(m7 >> 32));
            }
        }
    }
    __syncthreads();

    // ---- Compute phase: 64 rows from LDS (broadcast), nt stores. ----
    for (int r = 0; r < 64; ++r) {
        const uint4* xr4 = reinterpret_cast<const uint4*>(&xl[r * 16]);
        uint4 q0 = xr4[0], q1 = xr4[1], q2 = xr4[2], q3 = xr4[3];
        const uint32_t xv[16] = {q0.x, q0.y, q0.z, q0.w,
                                 q1.x, q1.y, q1.z, q1.w,
                                 q2.x, q2.y, q2.z, q2.w,
                                 q3.x, q3.y, q3.z, q3.w};
        uint32_t a0 = 0, a1 = 0, a2 = 0, a3 = 0;
#pragma unroll
        for (int i = 0; i < 16; ++i) {
            a0 ^= xv[i] & g[0][i];
            a1 ^= xv[i] & g[1][i];
            a2 ^= xv[i] & g[2][i];
            a3 ^= xv[i] & g[3][i];
        }
        f32x4 o;
        o.x = (float)(__popc(a0) & 1);
        o.y = (float)(__popc(a1) & 1);
        o.z = (float)(__popc(a2) & 1);
        o.w = (float)(__popc(a3) & 1);
        __builtin_nontemporal_store(
            o, reinterpret_cast<f32x4*>(out + (size_t)(b0 + r) * 1024) + tid);
    }
}

// ---------------------------------------------------------------------------
extern "C" void kernel_launch(void* const* d_in, const int* in_sizes, int n_in,
                              void* d_out, int out_size, void* d_ws, size_t ws_size,
                              hipStream_t stream) {
    const float* x = (const float*)d_in[0];   // [B][512]
    const float* G = (const float*)d_in[1];   // [N][512]
    float* out = (float*)d_out;

    const int B = 131072;
    // Workspace: gp (64 KiB)
    unsigned long long* gp64 = (unsigned long long*)d_ws;

    // Pack G: 2048 chunks, 4 waves/block -> 512 blocks.
    pack256_kernel<<<512, 256, 0, stream>>>(G, gp64, 2048);
    // Fused ballot-pack + encode: one block per 64 rows.
    gf2_fused_kernel<<<B / 64, 256, 0, stream>>>(
        x, (const uint32_t*)gp64, out);
}

// Round 15
// 155.972 us; speedup vs baseline: 1.4048x; 1.0216x over previous
//
#include <hip/hip_runtime.h>
#include <cstdint>

// GF(2) encoder: out[b][n] = parity( x_row[b] & g_row[n] ).
// B=131072, K=512, N=1024.
//
// R15 = R14 (159us: fused exclusive-row ballot-pack -> LDS -> broadcast
// compute, nt f32x4 stores) with ONE change: LB(256,4) -> LB(256,5).
// Compute-phase live VGPR ~92 (g 64 + q 16 + acc 4 + addr ~8) vs cap ~102
// at 5 blocks/CU -> +25% waves for HBM latency hiding.
// Spill sentinel: dur >= 300us (FETCH balloon) -> revert. Flat -> roofline.
// Component-major bit order identical to pack256 (G): chunk of 256 floats
// -> 4 u64, word j bit i = elem[i*4+j]; row = 2 chunks = 8 u64 = 16 u32.

typedef float f32x4 __attribute__((ext_vector_type(4)));

// ---------------------------------------------------------------------------
// Pack G only: one wave per 256-float chunk. nChunks = N*K/256 = 2048.
__global__ void pack256_kernel(const float* __restrict__ in,
                               unsigned long long* __restrict__ out,
                               int nChunks) {
    const int chunk = blockIdx.x * (blockDim.x >> 6) + (threadIdx.x >> 6);
    const int lane = threadIdx.x & 63;
    if (chunk >= nChunks) return;
    const float4 v =
        reinterpret_cast<const float4*>(in + (size_t)chunk * 256)[lane];
    unsigned long long m0 = __ballot(v.x != 0.0f);
    unsigned long long m1 = __ballot(v.y != 0.0f);
    unsigned long long m2 = __ballot(v.z != 0.0f);
    unsigned long long m3 = __ballot(v.w != 0.0f);
    if (lane == 0) {
        unsigned long long* o = out + (size_t)chunk * 4;
        o[0] = m0; o[1] = m1; o[2] = m2; o[3] = m3;
    }
}

// ---------------------------------------------------------------------------
// Fused encode: 256 threads, 4 cols/thread (block covers N=1024).
// Pack phase: wave wv ballot-packs rows [wv*16, wv*16+16) (exclusive),
// lane 0 writes 64B/row to LDS. One barrier. Compute phase: per row, 4
// broadcast ds_read_b128 deliver the packed row; AND/XOR vs G in VGPRs;
// nontemporal f32x4 stores.
__global__ __launch_bounds__(256, 5) void gf2_fused_kernel(
    const float* __restrict__ x,      // [B][512] 0/1 floats
    const uint32_t* __restrict__ gp,  // [N][16] packed G rows
    float* __restrict__ out) {        // [B][1024]
    __shared__ uint32_t xl[64 * 16];  // 64 rows x 16 u32 = 4 KiB

    const int tid = threadIdx.x;
    const int lane = tid & 63;
    const int wv = tid >> 6;
    const long long b0 = (long long)blockIdx.x * 64;

    // This thread's 4 G rows (64 VGPRs). G packed = 64 KiB -> L2-resident.
    uint32_t g[4][16];
#pragma unroll
    for (int j = 0; j < 4; ++j) {
        const uint4* gr =
            reinterpret_cast<const uint4*>(gp + (size_t)(tid * 4 + j) * 16);
        uint4 a = gr[0], b = gr[1], c = gr[2], d = gr[3];
        g[j][0] = a.x;  g[j][1] = a.y;  g[j][2] = a.z;  g[j][3] = a.w;
        g[j][4] = b.x;  g[j][5] = b.y;  g[j][6] = b.z;  g[j][7] = b.w;
        g[j][8] = c.x;  g[j][9] = c.y;  g[j][10] = c.z; g[j][11] = c.w;
        g[j][12] = d.x; g[j][13] = d.y; g[j][14] = d.z; g[j][15] = d.w;
    }

    // ---- Pack phase: 16 exclusive rows per wave, depth-1 prefetch. ----
    {
        const float* xr = x + (b0 + wv * 16) * 512 + lane * 4;
        float4 p0 = *reinterpret_cast<const float4*>(xr);
        float4 p1 = *reinterpret_cast<const float4*>(xr + 256);
        for (int r = 0; r < 16; ++r) {
            const float4 c0 = p0, c1 = p1;
            if (r < 15) {
                xr += 512;
                p0 = *reinterpret_cast<const float4*>(xr);
                p1 = *reinterpret_cast<const float4*>(xr + 256);
            }
            unsigned long long m0 = __ballot(c0.x != 0.0f);
            unsigned long long m1 = __ballot(c0.y != 0.0f);
            unsigned long long m2 = __ballot(c0.z != 0.0f);
            unsigned long long m3 = __ballot(c0.w != 0.0f);
            unsigned long long m4 = __ballot(c1.x != 0.0f);
            unsigned long long m5 = __ballot(c1.y != 0.0f);
            unsigned long long m6 = __ballot(c1.z != 0.0f);
            unsigned long long m7 = __ballot(c1.w != 0.0f);
            if (lane == 0) {
                uint4* dst = reinterpret_cast<uint4*>(&xl[(wv * 16 + r) * 16]);
                dst[0] = make_uint4((uint32_t)m0, (uint32_t)(m0 >> 32),
                                    (uint32_t)m1, (uint32_t)(m1 >> 32));
                dst[1] = make_uint4((uint32_t)m2, (uint32_t)(m2 >> 32),
                                    (uint32_t)m3, (uint32_t)(m3 >> 32));
                dst[2] = make_uint4((uint32_t)m4, (uint32_t)(m4 >> 32),
                                    (uint32_t)m5, (uint32_t)(m5 >> 32));
                dst[3] = make_uint4((uint32_t)m6, (uint32_t)(m6 >> 32),
                                    (uint32_t)m7, (uint32_t)(m7 >> 32));
            }
        }
    }
    __syncthreads();

    // ---- Compute phase: 64 rows from LDS (broadcast), nt stores. ----
    for (int r = 0; r < 64; ++r) {
        const uint4* xr4 = reinterpret_cast<const uint4*>(&xl[r * 16]);
        uint4 q0 = xr4[0], q1 = xr4[1], q2 = xr4[2], q3 = xr4[3];
        const uint32_t xv[16] = {q0.x, q0.y, q0.z, q0.w,
                                 q1.x, q1.y, q1.z, q1.w,
                                 q2.x, q2.y, q2.z, q2.w,
                                 q3.x, q3.y, q3.z, q3.w};
        uint32_t a0 = 0, a1 = 0, a2 = 0, a3 = 0;
#pragma unroll
        for (int i = 0; i < 16; ++i) {
            a0 ^= xv[i] & g[0][i];
            a1 ^= xv[i] & g[1][i];
            a2 ^= xv[i] & g[2][i];
            a3 ^= xv[i] & g[3][i];
        }
        f32x4 o;
        o.x = (float)(__popc(a0) & 1);
        o.y = (float)(__popc(a1) & 1);
        o.z = (float)(__popc(a2) & 1);
        o.w = (float)(__popc(a3) & 1);
        __builtin_nontemporal_store(
            o, reinterpret_cast<f32x4*>(out + (size_t)(b0 + r) * 1024) + tid);
    }
}

// ---------------------------------------------------------------------------
extern "C" void kernel_launch(void* const* d_in, const int* in_sizes, int n_in,
                              void* d_out, int out_size, void* d_ws, size_t ws_size,
                              hipStream_t stream) {
    const float* x = (const float*)d_in[0];   // [B][512]
    const float* G = (const float*)d_in[1];   // [N][512]
    float* out = (float*)d_out;

    const int B = 131072;
    // Workspace: gp (64 KiB)
    unsigned long long* gp64 = (unsigned long long*)d_ws;

    // Pack G: 2048 chunks, 4 waves/block -> 512 blocks.
    pack256_kernel<<<512, 256, 0, stream>>>(G, gp64, 2048);
    // Fused ballot-pack + encode: one block per 64 rows.
    gf2_fused_kernel<<<B / 64, 256, 0, stream>>>(
        x, (const uint32_t*)gp64, out);
}